// Round 14
// baseline (507.507 us; speedup 1.0000x reference)
//
#include <hip/hip_runtime.h>

typedef __attribute__((ext_vector_type(8))) _Float16 f16x8;
typedef __attribute__((ext_vector_type(4))) float f32x4;

#define HSTR 264   // fp16 per A/C row (528B): 16B-aligned, staggered banks

// ---- prep: weights -> fp16, fragment-contiguous (lane-major) into d_ws ----
__global__ __launch_bounds__(256) void prep_kernel(
    const float* __restrict__ gW0, const float* __restrict__ gW1,
    _Float16* __restrict__ W0c, _Float16* __restrict__ W1c)
{
  const int t = blockIdx.x * 256 + threadIdx.x;  // 0..65535
  {
    const int c = t >> 7, k = t & 127;           // c in [0,512), k in [0,128)
    const int dst = ((k >> 5) * 32 + (c >> 4)) * 512 +
                    (((k >> 3) & 3) * 16 + (c & 15)) * 8 + (k & 7);
    const int src = (k + ((c >= 256) ? 128 : 0)) * 256 + (c & 255);
    W0c[dst] = (_Float16)gW0[src];
  }
  {
    const int n = t >> 8, k = t & 255;           // n in [0,256), k in [0,256)
    const int dst = ((k >> 5) * 16 + (n >> 4)) * 512 +
                    (((k >> 3) & 3) * 16 + (n & 15)) * 8 + (k & 7);
    W1c[dst] = (_Float16)gW1[k * 256 + n];
  }
}

// ---- main: producer/consumer u via LDS, 256-AGPR W1, 1 tile/wave consume ----
// r13 diagnosis: consume was LDS-bound (every wave read ALL u: 1MB/block) +
// a pointless XOR swizzle (4.3M bank conflicts). Fix: (a) u layout is
// lane-linear (produce lane (lr,lg) computes exactly the fragment consume
// lane (lr,lg) needs -> write/read at l*16, zero conflicts); (b) each wave
// owns 128 N-cols (bw[8][8] = 256 AGPRs, pin proven r11-13) and consumes ONE
// tile per round: (tile = w>>1, col-half = w&1) -> consume reads drop 4x to
// 8 ds_read_b128/round/wave; per kk: 1 linear ds_read -> 8 independent asm
// MFMA chains. ~350 unified regs/wave -> 2 blocks/CU, 4 waves/SIMD.
__global__ __launch_bounds__(512, 4) void pair_kernel(
    const float* __restrict__ state,
    const _Float16* __restrict__ W0c, const float* __restrict__ gb0,
    const _Float16* __restrict__ W1c, const float* __restrict__ gb1,
    float* __restrict__ pooled)
{
  const int b   = blockIdx.x;
  const int tid = threadIdx.x;
  const int w   = tid >> 6;   // wave 0..7
  const int l   = tid & 63;
  const int lr  = l & 15;
  const int lg  = l >> 4;

  // [0, 8448) A_lds f16 [16][HSTR]; [8448, +32768) ubuf (C staged there, then
  // 4 x 8KB u-tiles, then 4KB pooled-reduce pool)
  __shared__ __align__(16) char smem[8448 + 32768];
  _Float16* A_lds = (_Float16*)smem;
  char*     ubuf  = smem + 8448;
  _Float16* C_st  = (_Float16*)ubuf;   // staging overlay, dead after creg capture

  const float* stb = state + (size_t)b * 2048;

  // ---------------- Phase 2: [A|C] = state[16x128] @ W0 (fp16 MFMA) ----------------
  f16x8 sfrag[4];
  #pragma unroll
  for (int kk = 0; kk < 4; ++kk) {
    const float* sp = stb + lr * 128 + kk * 32 + lg * 8;
    f32x4 s0 = *(const f32x4*)sp;
    f32x4 s1 = *(const f32x4*)(sp + 4);
    f16x8 f;
    f[0] = (_Float16)s0[0]; f[1] = (_Float16)s0[1];
    f[2] = (_Float16)s0[2]; f[3] = (_Float16)s0[3];
    f[4] = (_Float16)s1[0]; f[5] = (_Float16)s1[1];
    f[6] = (_Float16)s1[2]; f[7] = (_Float16)s1[3];
    sfrag[kk] = f;
  }

  const f32x4 z4 = {0.f, 0.f, 0.f, 0.f};
  f32x4 acc2[4];
  #pragma unroll
  for (int nt = 0; nt < 4; ++nt) acc2[nt] = z4;

  // wave w owns [A|C] cols [64w, 64w+64) for phase 2
  #pragma unroll
  for (int nt = 0; nt < 4; ++nt) {
    #pragma unroll
    for (int kk = 0; kk < 4; ++kk) {
      f16x8 bf = *(const f16x8*)(W0c + (size_t)((kk * 32 + 4 * w + nt) * 512 + l * 8));
      acc2[nt] = __builtin_amdgcn_mfma_f32_16x16x32_f16(sfrag[kk], bf, acc2[nt], 0, 0, 0);
    }
  }

  // W1 fragments: wave w owns N-cols [(w&1)*128, +128) -> 8nt x 8kk frags,
  // 256 AGPRs, opaque-pinned (r11-13: no remat, no spill).
  const int ch = w & 1;
  f16x8 bw[8][8];
  #pragma unroll
  for (int nt = 0; nt < 8; ++nt) {
    #pragma unroll
    for (int kk = 0; kk < 8; ++kk) {
      bw[nt][kk] = *(const f16x8*)(W1c + (size_t)((kk * 16 + ch * 8 + nt) * 512 + l * 8));
      asm volatile("" : "+a"(bw[nt][kk]));   // park in AGPR
    }
  }
  float gb1v[8];
  #pragma unroll
  for (int nt = 0; nt < 8; ++nt) gb1v[nt] = gb1[ch * 128 + nt * 16 + lr];

  // store phase-2 results as fp16 (C/D layout: col=lr, row=lg*4+r); fold gb0
  #pragma unroll
  for (int nt = 0; nt < 4; ++nt) {
    const int col = 64 * w + 16 * nt + lr;
    #pragma unroll
    for (int r = 0; r < 4; ++r) {
      const int row = lg * 4 + r;
      const float v = acc2[nt][r];
      if (col < 256) A_lds[row * HSTR + col]       = (_Float16)(v + gb0[col]);
      else           C_st[row * HSTR + col - 256]  = (_Float16)v;
    }
  }
  __syncthreads();

  // creg: only this wave's produce kk-half (w&1): kk = kh..kh+3 -> 16 VGPR
  const int kh = (w & 1) * 4;
  f16x8 creg[4];
  #pragma unroll
  for (int kq = 0; kq < 4; ++kq)
    creg[kq] = *(const f16x8*)&C_st[lr * HSTR + (kh + kq) * 32 + lg * 8];
  __syncthreads();   // C_st dead; ubuf writable

  const f16x8 zh = {(_Float16)0, (_Float16)0, (_Float16)0, (_Float16)0,
                    (_Float16)0, (_Float16)0, (_Float16)0, (_Float16)0};

  const int tc = w >> 1;             // tile this wave consumes (and co-produces)
  float pp[8];
  #pragma unroll
  for (int nt = 0; nt < 8; ++nt) pp[nt] = 0.f;

  #pragma unroll 1
  for (int g = 0; g < 4; ++g) {
    // ---- produce: wave w builds tile i = 4g + tc, kk-half kh..kh+3 ----
    // lane (lr,lg) computes u[j=lr][k=kk*32+lg*8..+8] == the fragment the
    // consuming lane (lr,lg) needs -> lane-linear layout, zero conflicts.
    {
      const int ip = 4 * g + tc;
      char* tb = ubuf + tc * 8192;
      #pragma unroll
      for (int kq = 0; kq < 4; ++kq) {
        const int kk = kh + kq;
        f16x8 av = *(const f16x8*)&A_lds[ip * HSTR + kk * 32 + lg * 8];  // bcast
        f16x8 u = __builtin_elementwise_max(av + creg[kq], zh);
        *(f16x8*)(tb + kk * 1024 + l * 16) = u;
      }
    }
    __syncthreads();   // all 4 tiles of this round ready

    // ---- consume: ONE tile, 128 N-cols: 8 ds_read -> 64 asm MFMA ----
    {
      const char* tb = ubuf + tc * 8192;
      f32x4 acc[8];
      #pragma unroll
      for (int nt = 0; nt < 8; ++nt) acc[nt] = z4;

      #pragma unroll
      for (int kk = 0; kk < 8; ++kk) {
        f16x8 uf = *(const f16x8*)(tb + kk * 1024 + l * 16);  // linear sweep
        // s_nop 3 covers VALU-write(acc init) -> first MFMA C-read hazard
        if (kk == 0)
          asm volatile("s_nop 3\n\tv_mfma_f32_16x16x32_f16 %0, %1, %2, %0"
                       : "+v"(acc[0]) : "v"(uf), "a"(bw[0][kk]));
        else
          asm volatile("v_mfma_f32_16x16x32_f16 %0, %1, %2, %0"
                       : "+v"(acc[0]) : "v"(uf), "a"(bw[0][kk]));
        #pragma unroll
        for (int nt = 1; nt < 8; ++nt)
          asm volatile("v_mfma_f32_16x16x32_f16 %0, %1, %2, %0"
                       : "+v"(acc[nt]) : "v"(uf), "a"(bw[nt][kk]));
      }
      asm volatile("s_nop 7\n\ts_nop 7");   // MFMA-write -> VALU-read spacing

      const int i = 4 * g + tc;
      #pragma unroll
      for (int nt = 0; nt < 8; ++nt) {
        #pragma unroll
        for (int r = 0; r < 4; ++r) {
          const int row = lg * 4 + r;       // = j
          const float v = fmaxf(acc[nt][r] + gb1v[nt], 0.f);
          pp[nt] += (row == i) ? 0.f : v;   // mask the (i,i) filler pair
        }
      }
    }
    __syncthreads();   // tiles consumed; next round may overwrite ubuf
  }

  // ---- pooled reduce: lane groups, then cross-wave via 4KB LDS pool ----
  float* pool = (float*)ubuf;   // [8][128], ubuf free after last barrier
  #pragma unroll
  for (int nt = 0; nt < 8; ++nt) {
    float v = pp[nt];
    v += __shfl_xor(v, 16);
    v += __shfl_xor(v, 32);
    if (lg == 0) pool[w * 128 + nt * 16 + lr] = v;
  }
  __syncthreads();
  if (tid < 256) {
    const int base = (tid >= 128) ? 1 : 0;
    const int c = tid & 127;
    pooled[(size_t)b * 256 + tid] =
        pool[(base + 0) * 128 + c] + pool[(base + 2) * 128 + c] +
        pool[(base + 4) * 128 + c] + pool[(base + 6) * 128 + c];
  }
}

// ---- f-MLP: 256 blocks x 4 batches (all CUs busy; weights L2-resident) ----
__global__ __launch_bounds__(256) void fmlp_kernel(
    const float* __restrict__ pooled,
    const float* __restrict__ fW0, const float* __restrict__ fb0,
    const float* __restrict__ fW1, const float* __restrict__ fb1,
    float* __restrict__ out)
{
  const int tid = threadIdx.x;
  const size_t b0 = (size_t)blockIdx.x * 4;
  __shared__ float pl[4][256];
  __shared__ float h1[4][256];

  #pragma unroll
  for (int q = 0; q < 4; ++q)
    pl[q][tid] = pooled[(b0 + q) * 256 + tid];
  __syncthreads();

  float acc[4] = {0.f, 0.f, 0.f, 0.f};
  #pragma unroll 8
  for (int k = 0; k < 256; ++k) {
    const float wv = fW0[(size_t)k * 256 + tid];
    #pragma unroll
    for (int q = 0; q < 4; ++q) acc[q] = fmaf(pl[q][k], wv, acc[q]);
  }
  #pragma unroll
  for (int q = 0; q < 4; ++q) h1[q][tid] = fmaxf(acc[q] + fb0[tid], 0.f);
  __syncthreads();

  float acc2[4] = {0.f, 0.f, 0.f, 0.f};
  #pragma unroll 8
  for (int k = 0; k < 256; ++k) {
    const float wv = fW1[(size_t)k * 256 + tid];
    #pragma unroll
    for (int q = 0; q < 4; ++q) acc2[q] = fmaf(h1[q][k], wv, acc2[q]);
  }
  #pragma unroll
  for (int q = 0; q < 4; ++q)
    out[(b0 + q) * 256 + tid] = fmaxf(acc2[q] + fb1[tid], 0.f);
}

extern "C" void kernel_launch(void* const* d_in, const int* in_sizes, int n_in,
                              void* d_out, int out_size, void* d_ws, size_t ws_size,
                              hipStream_t stream) {
  const float* state = (const float*)d_in[0];
  const float* gW0   = (const float*)d_in[1];
  const float* gb0   = (const float*)d_in[2];
  const float* gW1   = (const float*)d_in[3];
  const float* gb1   = (const float*)d_in[4];
  const float* fW0   = (const float*)d_in[5];
  const float* fb0   = (const float*)d_in[6];
  const float* fW1   = (const float*)d_in[7];
  const float* fb1   = (const float*)d_in[8];
  float* out = (float*)d_out;

  _Float16* W0c = (_Float16*)d_ws;                      // 65536 fp16 = 128KB
  _Float16* W1c = W0c + 65536;                          // 65536 fp16 = 128KB
  float* pooled = (float*)(W1c + 65536);                // 1024*256 f32 = 1MB

  const int Bn = in_sizes[0] / 2048;  // 1024

  prep_kernel<<<dim3(256), dim3(256), 0, stream>>>(gW0, gW1, W0c, W1c);
  pair_kernel<<<dim3(Bn), dim3(512), 0, stream>>>(state, W0c, gb0, W1c, gb1, pooled);
  fmlp_kernel<<<dim3(Bn / 4), dim3(256), 0, stream>>>(pooled, fW0, fb0, fW1, fb1, out);
}

// Round 15
// 70.778 us; speedup vs baseline: 7.1704x; 7.1704x over previous
//
#include <hip/hip_runtime.h>

typedef __attribute__((ext_vector_type(8))) _Float16 f16x8;
typedef __attribute__((ext_vector_type(4))) float f32x4;

#define HSTR 264   // fp16 per A/C row (528B): 16B-aligned, staggered banks

// ---- prep: weights -> fp16, fragment-contiguous (lane-major) into d_ws ----
__global__ __launch_bounds__(256) void prep_kernel(
    const float* __restrict__ gW0, const float* __restrict__ gW1,
    _Float16* __restrict__ W0c, _Float16* __restrict__ W1c)
{
  const int t = blockIdx.x * 256 + threadIdx.x;  // 0..65535
  {
    const int c = t >> 7, k = t & 127;           // c in [0,512), k in [0,128)
    const int dst = ((k >> 5) * 32 + (c >> 4)) * 512 +
                    (((k >> 3) & 3) * 16 + (c & 15)) * 8 + (k & 7);
    const int src = (k + ((c >= 256) ? 128 : 0)) * 256 + (c & 255);
    W0c[dst] = (_Float16)gW0[src];
  }
  {
    const int n = t >> 8, k = t & 255;           // n in [0,256), k in [0,256)
    const int dst = ((k >> 5) * 16 + (n >> 4)) * 512 +
                    (((k >> 3) & 3) * 16 + (n & 15)) * 8 + (k & 7);
    W1c[dst] = (_Float16)gW1[k * 256 + n];
  }
}

// ---- main: r13 producer/consumer structure + two proven fixes ----
// (a) u layout LANE-LINEAR (l*16): produce lane (lr,lg) computes exactly the
//     fragment consume lane (lr,lg) reads; r13's XOR swizzle of this perfect
//     sweep CAUSED the 4.3M bank conflicts (r14 evidence: linear -> 131K).
// (b) builtin MFMAs with AGPR-pinned bw (not asm volatile): volatile asm was
//     strictly program-ordered -- blocked ds_read hoisting, tile interleave,
//     software pipelining. LLVM reads MFMA B directly from AGPR (unified AV
//     class); pin (proven r11-r13 at 64 AGPRs, 4 waves/EU) prevents remat.
// Budget/wave: 64 AGPR + ~64 VGPR = 128 unified @ launch_bounds(512,4):
// 2 blocks/CU, 4 waves/SIMD. r14 lesson: NEVER pin more AGPRs than
// (512 / waves_per_eu) - VGPRs.
__global__ __launch_bounds__(512, 4) void pair_kernel(
    const float* __restrict__ state,
    const _Float16* __restrict__ W0c, const float* __restrict__ gb0,
    const _Float16* __restrict__ W1c, const float* __restrict__ gb1,
    float* __restrict__ pooled)
{
  const int b   = blockIdx.x;
  const int tid = threadIdx.x;
  const int w   = tid >> 6;   // wave 0..7
  const int l   = tid & 63;
  const int lr  = l & 15;
  const int lg  = l >> 4;

  // [0, 8448) A_lds f16 [16][HSTR]; [8448, +32768) ubuf (C staged there first,
  // then 4 x 8KB u-tiles, then 4KB pooled-reduce pool)
  __shared__ __align__(16) char smem[8448 + 32768];
  _Float16* A_lds = (_Float16*)smem;
  char*     ubuf  = smem + 8448;
  _Float16* C_st  = (_Float16*)ubuf;   // staging overlay, dead after creg capture

  const float* stb = state + (size_t)b * 2048;

  // ---------------- Phase 2: [A|C] = state[16x128] @ W0 (fp16 MFMA) ----------------
  f16x8 sfrag[4];
  #pragma unroll
  for (int kk = 0; kk < 4; ++kk) {
    const float* sp = stb + lr * 128 + kk * 32 + lg * 8;
    f32x4 s0 = *(const f32x4*)sp;
    f32x4 s1 = *(const f32x4*)(sp + 4);
    f16x8 f;
    f[0] = (_Float16)s0[0]; f[1] = (_Float16)s0[1];
    f[2] = (_Float16)s0[2]; f[3] = (_Float16)s0[3];
    f[4] = (_Float16)s1[0]; f[5] = (_Float16)s1[1];
    f[6] = (_Float16)s1[2]; f[7] = (_Float16)s1[3];
    sfrag[kk] = f;
  }

  const f32x4 z4 = {0.f, 0.f, 0.f, 0.f};
  f32x4 acc2[4];
  #pragma unroll
  for (int nt = 0; nt < 4; ++nt) acc2[nt] = z4;

  // wave w owns [A|C] cols [64w, 64w+64) for phase 2
  #pragma unroll
  for (int nt = 0; nt < 4; ++nt) {
    #pragma unroll
    for (int kk = 0; kk < 4; ++kk) {
      f16x8 bf = *(const f16x8*)(W0c + (size_t)((kk * 32 + 4 * w + nt) * 512 + l * 8));
      acc2[nt] = __builtin_amdgcn_mfma_f32_16x16x32_f16(sfrag[kk], bf, acc2[nt], 0, 0, 0);
    }
  }

  // W1 fragments for this wave's N-cols [32w,32w+32): AGPR-pinned, no remat
  f16x8 bw[2][8];
  #pragma unroll
  for (int nt = 0; nt < 2; ++nt) {
    #pragma unroll
    for (int kk = 0; kk < 8; ++kk) {
      bw[nt][kk] = *(const f16x8*)(W1c + (size_t)((kk * 16 + 2 * w + nt) * 512 + l * 8));
      asm volatile("" : "+a"(bw[nt][kk]));   // park in AGPR (64 total: proven safe)
    }
  }
  float gb1v[2];
  gb1v[0] = gb1[32 * w + lr];
  gb1v[1] = gb1[32 * w + 16 + lr];

  // store phase-2 results as fp16 (C/D layout: col=lr, row=lg*4+r); fold gb0
  #pragma unroll
  for (int nt = 0; nt < 4; ++nt) {
    const int col = 64 * w + 16 * nt + lr;
    #pragma unroll
    for (int r = 0; r < 4; ++r) {
      const int row = lg * 4 + r;
      const float v = acc2[nt][r];
      if (col < 256) A_lds[row * HSTR + col]       = (_Float16)(v + gb0[col]);
      else           C_st[row * HSTR + col - 256]  = (_Float16)v;
    }
  }
  __syncthreads();

  // creg: only this wave's produce kk-half (w&1): kk = kh..kh+3 -> 16 VGPR
  const int kh = (w & 1) * 4;
  f16x8 creg[4];
  #pragma unroll
  for (int kq = 0; kq < 4; ++kq)
    creg[kq] = *(const f16x8*)&C_st[lr * HSTR + (kh + kq) * 32 + lg * 8];
  __syncthreads();   // C_st dead; ubuf writable

  const f16x8 zh = {(_Float16)0, (_Float16)0, (_Float16)0, (_Float16)0,
                    (_Float16)0, (_Float16)0, (_Float16)0, (_Float16)0};

  const int tc = w >> 1;             // tile this wave co-produces
  float pp0 = 0.f, pp1 = 0.f;

  #pragma unroll 1
  for (int g = 0; g < 4; ++g) {
    // ---- produce: wave w builds tile i = 4g + tc, kk in [kh, kh+4) ----
    // lane-linear: lane (lr,lg) writes u[j=lr][k=kk*32+lg*8..+8] at l*16.
    {
      const int ip = 4 * g + tc;
      char* tb = ubuf + tc * 8192;
      #pragma unroll
      for (int kq = 0; kq < 4; ++kq) {
        const int kk = kh + kq;
        f16x8 av = *(const f16x8*)&A_lds[ip * HSTR + kk * 32 + lg * 8];  // bcast
        f16x8 u = __builtin_elementwise_max(av + creg[kq], zh);
        *(f16x8*)(tb + kk * 1024 + l * 16) = u;
      }
    }
    __syncthreads();   // all 4 tiles of this round ready

    // ---- consume: all 4 tiles, ds_read_b128 (linear sweep) -> builtin MFMA ----
    #pragma unroll
    for (int t = 0; t < 4; ++t) {
      const char* tb = ubuf + t * 8192;
      f32x4 a0 = z4, a1 = z4;
      #pragma unroll
      for (int kk = 0; kk < 8; ++kk) {
        f16x8 uf = *(const f16x8*)(tb + kk * 1024 + l * 16);
        a0 = __builtin_amdgcn_mfma_f32_16x16x32_f16(uf, bw[0][kk], a0, 0, 0, 0);
        a1 = __builtin_amdgcn_mfma_f32_16x16x32_f16(uf, bw[1][kk], a1, 0, 0, 0);
      }
      const int i = 4 * g + t;
      #pragma unroll
      for (int r = 0; r < 4; ++r) {
        const int row = lg * 4 + r;       // = j
        const float v0 = fmaxf(a0[r] + gb1v[0], 0.f);
        const float v1 = fmaxf(a1[r] + gb1v[1], 0.f);
        pp0 += (row == i) ? 0.f : v0;     // mask the (i,i) filler pair
        pp1 += (row == i) ? 0.f : v1;
      }
    }
    __syncthreads();   // tiles consumed; next round may overwrite ubuf
  }

  // reduce the 4 lane-groups (disjoint j subsets, same col), write pooled
  {
    float v = pp0;
    v += __shfl_xor(v, 16);
    v += __shfl_xor(v, 32);
    if (lg == 0) pooled[(size_t)b * 256 + 32 * w + lr] = v;
  }
  {
    float v = pp1;
    v += __shfl_xor(v, 16);
    v += __shfl_xor(v, 32);
    if (lg == 0) pooled[(size_t)b * 256 + 32 * w + 16 + lr] = v;
  }
}

// ---- f-MLP: 256 blocks x 4 batches (all CUs busy; weights L2-resident) ----
__global__ __launch_bounds__(256) void fmlp_kernel(
    const float* __restrict__ pooled,
    const float* __restrict__ fW0, const float* __restrict__ fb0,
    const float* __restrict__ fW1, const float* __restrict__ fb1,
    float* __restrict__ out)
{
  const int tid = threadIdx.x;
  const size_t b0 = (size_t)blockIdx.x * 4;
  __shared__ float pl[4][256];
  __shared__ float h1[4][256];

  #pragma unroll
  for (int q = 0; q < 4; ++q)
    pl[q][tid] = pooled[(b0 + q) * 256 + tid];
  __syncthreads();

  float acc[4] = {0.f, 0.f, 0.f, 0.f};
  #pragma unroll 8
  for (int k = 0; k < 256; ++k) {
    const float wv = fW0[(size_t)k * 256 + tid];
    #pragma unroll
    for (int q = 0; q < 4; ++q) acc[q] = fmaf(pl[q][k], wv, acc[q]);
  }
  #pragma unroll
  for (int q = 0; q < 4; ++q) h1[q][tid] = fmaxf(acc[q] + fb0[tid], 0.f);
  __syncthreads();

  float acc2[4] = {0.f, 0.f, 0.f, 0.f};
  #pragma unroll 8
  for (int k = 0; k < 256; ++k) {
    const float wv = fW1[(size_t)k * 256 + tid];
    #pragma unroll
    for (int q = 0; q < 4; ++q) acc2[q] = fmaf(h1[q][k], wv, acc2[q]);
  }
  #pragma unroll
  for (int q = 0; q < 4; ++q)
    out[(b0 + q) * 256 + tid] = fmaxf(acc2[q] + fb1[tid], 0.f);
}

extern "C" void kernel_launch(void* const* d_in, const int* in_sizes, int n_in,
                              void* d_out, int out_size, void* d_ws, size_t ws_size,
                              hipStream_t stream) {
  const float* state = (const float*)d_in[0];
  const float* gW0   = (const float*)d_in[1];
  const float* gb0   = (const float*)d_in[2];
  const float* gW1   = (const float*)d_in[3];
  const float* gb1   = (const float*)d_in[4];
  const float* fW0   = (const float*)d_in[5];
  const float* fb0   = (const float*)d_in[6];
  const float* fW1   = (const float*)d_in[7];
  const float* fb1   = (const float*)d_in[8];
  float* out = (float*)d_out;

  _Float16* W0c = (_Float16*)d_ws;                      // 65536 fp16 = 128KB
  _Float16* W1c = W0c + 65536;                          // 65536 fp16 = 128KB
  float* pooled = (float*)(W1c + 65536);                // 1024*256 f32 = 1MB

  const int Bn = in_sizes[0] / 2048;  // 1024

  prep_kernel<<<dim3(256), dim3(256), 0, stream>>>(gW0, gW1, W0c, W1c);
  pair_kernel<<<dim3(Bn), dim3(512), 0, stream>>>(state, W0c, gb0, W1c, gb1, pooled);
  fmlp_kernel<<<dim3(Bn / 4), dim3(256), 0, stream>>>(pooled, fW0, fb0, fW1, fb1, out);
}